// Round 1
// baseline (1390.524 us; speedup 1.0000x reference)
//
#include <hip/hip_runtime.h>
#include <hip/hip_bf16.h>

#define NN 50000      // nodes
#define NE 200000     // edges
#define NGR 500       // graphs
#define HD 128        // hidden
#define CDIM 256      // H*DH
#define NLAY 4
#define NVOC 30

static constexpr float BN_INV = 0.9999950000374997f;  // 1/sqrt(1+1e-5)

// ---------------- tables: x0table[30][128] = emb MLP ----------------
__global__ __launch_bounds__(128) void k_tables_node(
    const float* __restrict__ ne, const float* __restrict__ w1, const float* __restrict__ b1,
    const float* __restrict__ g1, const float* __restrict__ bt1,
    const float* __restrict__ w2, const float* __restrict__ b2,
    const float* __restrict__ g0, const float* __restrict__ bt0,
    float* __restrict__ x0tab)
{
    int r = blockIdx.x, d = threadIdx.x;
    __shared__ float emb[HD], t1[HD];
    emb[d] = ne[r * HD + d];
    __syncthreads();
    float acc = b1[d];
    for (int k = 0; k < HD; ++k) acc += emb[k] * w1[k * HD + d];
    float t = fmaxf(acc * BN_INV * g1[d] + bt1[d], 0.f);
    t1[d] = t;
    __syncthreads();
    float acc2 = b2[d];
    for (int k = 0; k < HD; ++k) acc2 += t1[k] * w2[k * HD + d];
    x0tab[r * HD + d] = fmaxf(acc2 * BN_INV * g0[d] + bt0[d], 0.f);
}

// ---------------- tables: etab[l][30][256] = node_emb @ We[l] ----------------
__global__ __launch_bounds__(256) void k_tables_edge(
    const float* __restrict__ ne, const float* __restrict__ We, float* __restrict__ etab)
{
    int la = blockIdx.x;              // l*NVOC + a
    int l = la / NVOC, a = la % NVOC;
    int c = threadIdx.x;              // 0..255
    __shared__ float emb[HD];
    if (c < HD) emb[c] = ne[a * HD + c];
    __syncthreads();
    const float* W = We + (size_t)l * HD * CDIM;
    float acc = 0.f;
    for (int k = 0; k < HD; ++k) acc += emb[k] * W[k * CDIM + c];
    etab[(size_t)la * CDIM + c] = acc;
}

// ---------------- CSR build ----------------
__global__ void k_hist_dst(const int* __restrict__ ei, int* __restrict__ cnt)
{
    int e = blockIdx.x * blockDim.x + threadIdx.x;
    if (e < NE) atomicAdd(&cnt[ei[NE + e]], 1);
}

__global__ __launch_bounds__(1024) void k_exscan(
    const int* __restrict__ in, int* __restrict__ out, int* __restrict__ out2, int n)
{
    __shared__ int sm[1024];
    int tid = threadIdx.x;
    int ch = (n + 1023) >> 10;
    int beg = tid * ch, end = min(beg + ch, n);
    int s = 0;
    for (int i = beg; i < end; ++i) s += in[i];
    sm[tid] = s;
    __syncthreads();
    for (int off = 1; off < 1024; off <<= 1) {
        int t = (tid >= off) ? sm[tid - off] : 0;
        __syncthreads();
        sm[tid] += t;
        __syncthreads();
    }
    int run = sm[tid] - s;  // exclusive prefix of this chunk
    for (int i = beg; i < end; ++i) { out[i] = run; if (out2) out2[i] = run; run += in[i]; }
    if (tid == 1023) { out[n] = sm[1023]; if (out2) out2[n] = sm[1023]; }
}

__global__ void k_scatter(const int* __restrict__ ei, const int* __restrict__ ea,
                          int* __restrict__ wof, int* __restrict__ csrc, int* __restrict__ cea)
{
    int e = blockIdx.x * blockDim.x + threadIdx.x;
    if (e < NE) {
        int d = ei[NE + e];
        int pos = atomicAdd(&wof[d], 1);
        csrc[pos] = ei[e];
        cea[pos]  = ea[e];
    }
}

// graph boundaries: batch is sorted, binary-search first index with batch[i] >= g
__global__ void k_gptr(const int* __restrict__ batch, int* __restrict__ gptr)
{
    int g = blockIdx.x * blockDim.x + threadIdx.x;
    if (g > NGR) return;
    if (g == NGR) { gptr[g] = NN; return; }
    int lo = 0, hi = NN;
    while (lo < hi) { int mid = (lo + hi) >> 1; if (batch[mid] < g) lo = mid + 1; else hi = mid; }
    gptr[g] = lo;
}

// ---------------- x0[n] = x0table[x[n]] ----------------
__global__ void k_x0(const int* __restrict__ x, const float* __restrict__ tab, float* __restrict__ x0)
{
    int idx = blockIdx.x * blockDim.x + threadIdx.x;  // NN*32 float4 slots
    if (idx >= NN * 32) return;
    int n = idx >> 5, c = idx & 31;
    float4 v = *(const float4*)&tab[x[n] * HD + c * 4];
    *(float4*)&x0[(size_t)n * HD + c * 4] = v;
}

// ---------------- fused QKVR GEMM: A[N,128] x {Wq,Wk,Wv,Wr} ----------------
#define GSTEP(ax_, w_) \
    acc[0][0] += a0.ax_ * w_.x; acc[0][1] += a0.ax_ * w_.y; acc[0][2] += a0.ax_ * w_.z; acc[0][3] += a0.ax_ * w_.w; \
    acc[1][0] += a1.ax_ * w_.x; acc[1][1] += a1.ax_ * w_.y; acc[1][2] += a1.ax_ * w_.z; acc[1][3] += a1.ax_ * w_.w; \
    acc[2][0] += a2.ax_ * w_.x; acc[2][1] += a2.ax_ * w_.y; acc[2][2] += a2.ax_ * w_.z; acc[2][3] += a2.ax_ * w_.w; \
    acc[3][0] += a3.ax_ * w_.x; acc[3][1] += a3.ax_ * w_.y; acc[3][2] += a3.ax_ * w_.z; acc[3][3] += a3.ax_ * w_.w;

__global__ __launch_bounds__(256) void k_gemm_qkvr(
    const float* __restrict__ A,
    const float* __restrict__ Wq, const float* __restrict__ Wk,
    const float* __restrict__ Wv, const float* __restrict__ Wr,
    float* __restrict__ Q, float* __restrict__ K, float* __restrict__ V, float* __restrict__ R)
{
    __shared__ float As[64][132];
    int t = blockIdx.y;  // 0..13: 0-3 Q, 4-7 K, 8-11 V, 12-13 R
    const float* W; float* C; int ncols, colbase;
    if (t < 12) {
        int which = t >> 2;
        W = (which == 0) ? Wq : (which == 1) ? Wk : Wv;
        C = (which == 0) ? Q  : (which == 1) ? K  : V;
        ncols = CDIM; colbase = (t & 3) * 64;
    } else {
        W = Wr; C = R; ncols = HD; colbase = (t - 12) * 64;
    }
    int row0 = blockIdx.x * 64;
    int tid = threadIdx.x;
#pragma unroll
    for (int it = 0; it < 8; ++it) {
        int idx = tid + it * 256;
        int r = idx >> 5, c4 = idx & 31;
        int gr = row0 + r;
        float4 v = {0.f, 0.f, 0.f, 0.f};
        if (gr < NN) v = *(const float4*)&A[(size_t)gr * HD + c4 * 4];
        *(float4*)&As[r][c4 * 4] = v;
    }
    __syncthreads();
    int tx = tid & 15, ty = tid >> 4;
    int rr0 = ty * 4, cc0 = tx * 4;
    float acc[4][4] = {};
    const float* Wp = W + colbase + cc0;
#pragma unroll 2
    for (int k4 = 0; k4 < 32; ++k4) {
        float4 a0 = *(const float4*)&As[rr0 + 0][k4 * 4];
        float4 a1 = *(const float4*)&As[rr0 + 1][k4 * 4];
        float4 a2 = *(const float4*)&As[rr0 + 2][k4 * 4];
        float4 a3 = *(const float4*)&As[rr0 + 3][k4 * 4];
        float4 w0 = *(const float4*)&Wp[(size_t)(k4 * 4 + 0) * ncols];
        float4 w1 = *(const float4*)&Wp[(size_t)(k4 * 4 + 1) * ncols];
        float4 w2 = *(const float4*)&Wp[(size_t)(k4 * 4 + 2) * ncols];
        float4 w3 = *(const float4*)&Wp[(size_t)(k4 * 4 + 3) * ncols];
        GSTEP(x, w0) GSTEP(y, w1) GSTEP(z, w2) GSTEP(w, w3)
    }
#pragma unroll
    for (int r = 0; r < 4; ++r) {
        int gr = row0 + rr0 + r;
        if (gr < NN) {
            float4 o = {acc[r][0], acc[r][1], acc[r][2], acc[r][3]};
            *(float4*)&C[(size_t)gr * ncols + colbase + cc0] = o;
        }
    }
}

// ---------------- per-node attention: wave per dst node, online softmax ----------------
__global__ __launch_bounds__(256) void k_edge(
    const float* __restrict__ Q, const float* __restrict__ K, const float* __restrict__ V,
    const float* __restrict__ R, const float* __restrict__ etab, const float* __restrict__ attL,
    const float* __restrict__ biasL, const float* __restrict__ x0,
    const int* __restrict__ rowptr, const int* __restrict__ csrc, const int* __restrict__ cea,
    float* __restrict__ hout)
{
    int wave = (blockIdx.x * blockDim.x + threadIdx.x) >> 6;
    if (wave >= NN) return;
    int n = wave;
    int lane = threadIdx.x & 63;
    int head = lane >> 5, sub = lane & 31;
    int col = head * HD + sub * 4;

    float4 q4 = *(const float4*)&Q[(size_t)n * CDIM + col];
    float4 a4 = *(const float4*)&attL[col];

    float m = -INFINITY, l = 0.f;
    float4 acc = {0.f, 0.f, 0.f, 0.f};

    int beg = rowptr[n], end = rowptr[n + 1];
    for (int idx = beg; idx < end; ++idx) {
        int s = csrc[idx], a = cea[idx];
        float4 k4 = *(const float4*)&K[(size_t)s * CDIM + col];
        float4 e4 = *(const float4*)&etab[a * CDIM + col];
        float zx = q4.x + k4.x + e4.x; zx = (zx > 0.f) ? zx : 0.2f * zx;
        float zy = q4.y + k4.y + e4.y; zy = (zy > 0.f) ? zy : 0.2f * zy;
        float zz = q4.z + k4.z + e4.z; zz = (zz > 0.f) ? zz : 0.2f * zz;
        float zw = q4.w + k4.w + e4.w; zw = (zw > 0.f) ? zw : 0.2f * zw;
        float p = zx * a4.x + zy * a4.y + zz * a4.z + zw * a4.w;
        p += __shfl_xor(p, 16); p += __shfl_xor(p, 8);
        p += __shfl_xor(p, 4);  p += __shfl_xor(p, 2); p += __shfl_xor(p, 1);
        // p = score of this edge for this head (all 32 lanes of the head agree)
        float4 v4 = *(const float4*)&V[(size_t)s * CDIM + col];
        float wx = v4.x + e4.x, wy = v4.y + e4.y, wz = v4.z + e4.z, ww = v4.w + e4.w;
        float mn = fmaxf(m, p);
        float sc = __expf(m - mn);     // exp(-inf)=0 on first edge
        float pe = __expf(p - mn);
        acc.x = acc.x * sc + pe * wx;
        acc.y = acc.y * sc + pe * wy;
        acc.z = acc.z * sc + pe * wz;
        acc.w = acc.w * sc + pe * ww;
        l = l * sc + pe;
        m = mn;
    }
    float invl = (l > 0.f) ? 1.0f / l : 0.f;
    float ax = acc.x * invl, ay = acc.y * invl, az = acc.z * invl, aw = acc.w * invl;
    // mean over heads: pair lane <-> lane^32
    ax = 0.5f * (ax + __shfl_xor(ax, 32));
    ay = 0.5f * (ay + __shfl_xor(ay, 32));
    az = 0.5f * (az + __shfl_xor(az, 32));
    aw = 0.5f * (aw + __shfl_xor(aw, 32));
    if (head == 0) {
        size_t o = (size_t)n * HD + sub * 4;
        float4 r4 = *(const float4*)&R[o];
        float4 b4 = *(const float4*)&biasL[sub * 4];
        float4 x4 = *(const float4*)&x0[o];
        float ox = 0.9f * fmaxf(ax + r4.x + b4.x, 0.f) + 0.1f * x4.x;
        float oy = 0.9f * fmaxf(ay + r4.y + b4.y, 0.f) + 0.1f * x4.y;
        float oz = 0.9f * fmaxf(az + r4.z + b4.z, 0.f) + 0.1f * x4.z;
        float ow = 0.9f * fmaxf(aw + r4.w + b4.w, 0.f) + 0.1f * x4.w;
        float4 o4 = {ox, oy, oz, ow};
        *(float4*)&hout[o] = o4;
    }
}

// ---------------- pooling: block per graph, sum one 128-slice ----------------
__global__ __launch_bounds__(128) void k_pool(
    const float* __restrict__ src, const int* __restrict__ gptr,
    float* __restrict__ gsum, int slice)
{
    int g = blockIdx.x, d = threadIdx.x;
    int beg = gptr[g], end = gptr[g + 1];
    float s = 0.f;
    for (int n = beg; n < end; ++n) s += src[(size_t)n * HD + d];
    gsum[(size_t)g * 640 + slice * HD + d] = s;
}

// ---------------- final MLP: g[640] -> 128 -> 1 ----------------
__global__ __launch_bounds__(128) void k_out(
    const float* __restrict__ gsum, const int* __restrict__ gptr,
    const float* __restrict__ w1, const float* __restrict__ b1,
    const float* __restrict__ g1, const float* __restrict__ bt1,
    const float* __restrict__ w2, const float* __restrict__ b2,
    float* __restrict__ out)
{
    int g = blockIdx.x, d = threadIdx.x;
    __shared__ float row[640];
    __shared__ float red[2];
    int c = gptr[g + 1] - gptr[g];
    float invc = 1.0f / (float)max(c, 1);
    for (int j = d; j < 640; j += 128) row[j] = gsum[(size_t)g * 640 + j] * invc;
    __syncthreads();
    float acc = b1[d];
    for (int j = 0; j < 640; ++j) acc += row[j] * w1[j * HD + d];
    float val = fmaxf(acc * BN_INV * g1[d] + bt1[d], 0.f);
    float part = val * w2[d];
    part += __shfl_xor(part, 32); part += __shfl_xor(part, 16);
    part += __shfl_xor(part, 8);  part += __shfl_xor(part, 4);
    part += __shfl_xor(part, 2);  part += __shfl_xor(part, 1);
    if ((threadIdx.x & 63) == 0) red[threadIdx.x >> 6] = part;
    __syncthreads();
    if (threadIdx.x == 0) out[g] = red[0] + red[1] + b2[0];
}

// ---------------- launch ----------------
extern "C" void kernel_launch(void* const* d_in, const int* in_sizes, int n_in,
                              void* d_out, int out_size, void* d_ws, size_t ws_size,
                              hipStream_t stream)
{
    const int*   x        = (const int*)d_in[0];
    const int*   ei       = (const int*)d_in[1];
    const int*   ea       = (const int*)d_in[2];
    const int*   batch    = (const int*)d_in[3];
    const float* node_emb = (const float*)d_in[4];
    const float* emb_w1   = (const float*)d_in[5];
    const float* emb_b1   = (const float*)d_in[6];
    const float* emb_g1   = (const float*)d_in[7];
    const float* emb_bt1  = (const float*)d_in[8];
    const float* emb_w2   = (const float*)d_in[9];
    const float* emb_b2   = (const float*)d_in[10];
    const float* bn0_g    = (const float*)d_in[11];
    const float* bn0_b    = (const float*)d_in[12];
    const float* Wq       = (const float*)d_in[13];
    const float* Wk       = (const float*)d_in[14];
    const float* Wv       = (const float*)d_in[15];
    const float* We       = (const float*)d_in[16];
    const float* att      = (const float*)d_in[17];
    const float* Wroot    = (const float*)d_in[18];
    const float* bias     = (const float*)d_in[19];
    const float* out_w1   = (const float*)d_in[20];
    const float* out_b1   = (const float*)d_in[21];
    const float* out_g1   = (const float*)d_in[22];
    const float* out_bt1  = (const float*)d_in[23];
    const float* out_w2   = (const float*)d_in[24];
    const float* out_b2   = (const float*)d_in[25];

    char* wp = (char*)d_ws;
    auto alloc = [&](size_t bytes) -> void* {
        void* p = (void*)wp;
        wp += (bytes + 255) & ~(size_t)255;
        return p;
    };
    float* x0    = (float*)alloc((size_t)NN * HD * 4);
    float* hA    = (float*)alloc((size_t)NN * HD * 4);
    float* hB    = (float*)alloc((size_t)NN * HD * 4);
    float* Qb    = (float*)alloc((size_t)NN * CDIM * 4);
    float* Kb    = (float*)alloc((size_t)NN * CDIM * 4);
    float* Vb    = (float*)alloc((size_t)NN * CDIM * 4);
    float* Rb    = (float*)alloc((size_t)NN * HD * 4);
    float* x0tab = (float*)alloc((size_t)NVOC * HD * 4);
    float* etab  = (float*)alloc((size_t)NLAY * NVOC * CDIM * 4);
    int*   cnt   = (int*)alloc((size_t)NN * 4);
    int*   rowp  = (int*)alloc((size_t)(NN + 1) * 4);
    int*   wof   = (int*)alloc((size_t)(NN + 1) * 4);
    int*   csrc  = (int*)alloc((size_t)NE * 4);
    int*   ceaB  = (int*)alloc((size_t)NE * 4);
    int*   gptr  = (int*)alloc((size_t)(NGR + 1) * 4);
    float* gsum  = (float*)alloc((size_t)NGR * 640 * 4);

    hipMemsetAsync(cnt, 0, (size_t)NN * 4, stream);

    k_tables_node<<<NVOC, 128, 0, stream>>>(node_emb, emb_w1, emb_b1, emb_g1, emb_bt1,
                                            emb_w2, emb_b2, bn0_g, bn0_b, x0tab);
    k_tables_edge<<<NLAY * NVOC, 256, 0, stream>>>(node_emb, We, etab);
    k_hist_dst<<<(NE + 255) / 256, 256, 0, stream>>>(ei, cnt);
    k_exscan<<<1, 1024, 0, stream>>>(cnt, rowp, wof, NN);
    k_scatter<<<(NE + 255) / 256, 256, 0, stream>>>(ei, ea, wof, csrc, ceaB);
    k_gptr<<<(NGR + 1 + 255) / 256, 256, 0, stream>>>(batch, gptr);
    k_x0<<<(NN * 32 + 255) / 256, 256, 0, stream>>>(x, x0tab, x0);
    k_pool<<<NGR, 128, 0, stream>>>(x0, gptr, gsum, 0);

    const float* hin = x0;
    float* houts[NLAY] = {hA, hB, hA, hB};
    for (int l = 0; l < NLAY; ++l) {
        k_gemm_qkvr<<<dim3((NN + 63) / 64, 14), 256, 0, stream>>>(
            hin,
            Wq + (size_t)l * HD * CDIM, Wk + (size_t)l * HD * CDIM,
            Wv + (size_t)l * HD * CDIM, Wroot + (size_t)l * HD * HD,
            Qb, Kb, Vb, Rb);
        k_edge<<<(NN * 64 + 255) / 256, 256, 0, stream>>>(
            Qb, Kb, Vb, Rb,
            etab + (size_t)l * NVOC * CDIM, att + (size_t)l * CDIM, bias + (size_t)l * HD,
            x0, rowp, csrc, ceaB, houts[l]);
        k_pool<<<NGR, 128, 0, stream>>>(houts[l], gptr, gsum, l + 1);
        hin = houts[l];
    }
    k_out<<<NGR, 128, 0, stream>>>(gsum, gptr, out_w1, out_b1, out_g1, out_bt1,
                                   out_w2, out_b2, (float*)d_out);
}

// Round 2
// 757.294 us; speedup vs baseline: 1.8362x; 1.8362x over previous
//
#include <hip/hip_runtime.h>
#include <hip/hip_bf16.h>

#define NN 50000      // nodes
#define NE 200000     // edges
#define NGR 500       // graphs
#define HD 128        // hidden
#define CDIM 256      // H*DH
#define NLAY 4
#define NVOC 30
#define NCAT 896      // 256*3 + 128 : Q|K|V|R concatenated

static constexpr float BN_INV = 0.9999950000374997f;  // 1/sqrt(1+1e-5)

typedef __attribute__((ext_vector_type(8))) short bf16x8;
typedef __attribute__((ext_vector_type(4))) float f32x4;

__device__ __forceinline__ float bf2f(unsigned short u) {
    return __uint_as_float(((unsigned)u) << 16);
}
__device__ __forceinline__ unsigned short f2bf(float f) {
    union { __hip_bfloat16 h; unsigned short u; } cv;
    cv.h = __float2bfloat16(f);
    return cv.u;
}

// ---------------- tables: x0table[30][128] = emb MLP (fp32) ----------------
__global__ __launch_bounds__(128) void k_tables_node(
    const float* __restrict__ ne, const float* __restrict__ w1, const float* __restrict__ b1,
    const float* __restrict__ g1, const float* __restrict__ bt1,
    const float* __restrict__ w2, const float* __restrict__ b2,
    const float* __restrict__ g0, const float* __restrict__ bt0,
    float* __restrict__ x0tab)
{
    int r = blockIdx.x, d = threadIdx.x;
    __shared__ float emb[HD], t1[HD];
    emb[d] = ne[r * HD + d];
    __syncthreads();
    float acc = b1[d];
    for (int k = 0; k < HD; ++k) acc += emb[k] * w1[k * HD + d];
    float t = fmaxf(acc * BN_INV * g1[d] + bt1[d], 0.f);
    t1[d] = t;
    __syncthreads();
    float acc2 = b2[d];
    for (int k = 0; k < HD; ++k) acc2 += t1[k] * w2[k * HD + d];
    x0tab[r * HD + d] = fmaxf(acc2 * BN_INV * g0[d] + bt0[d], 0.f);
}

// ---------------- tables: etab[l][30][256] bf16 = node_emb @ We[l] ----------------
__global__ __launch_bounds__(256) void k_tables_edge(
    const float* __restrict__ ne, const float* __restrict__ We, unsigned short* __restrict__ etab)
{
    int la = blockIdx.x;              // l*NVOC + a
    int l = la / NVOC, a = la % NVOC;
    int c = threadIdx.x;              // 0..255
    __shared__ float emb[HD];
    if (c < HD) emb[c] = ne[a * HD + c];
    __syncthreads();
    const float* W = We + (size_t)l * HD * CDIM;
    float acc = 0.f;
    for (int k = 0; k < HD; ++k) acc += emb[k] * W[k * CDIM + c];
    etab[(size_t)la * CDIM + c] = f2bf(acc);
}

// ---------------- pack weights: Wpk[l][kb][jb][lane][8] bf16 ----------------
// fragment mapping for mfma_f32_16x16x32_bf16 B-operand:
//   k = kb*32 + 8*(lane>>4) + t ; j = jb*16 + (lane&15)
// cat columns: j<256 Wq | <512 Wk | <768 Wv | <896 Wroot
__global__ __launch_bounds__(64) void k_packw(
    const float* __restrict__ Wq, const float* __restrict__ Wk,
    const float* __restrict__ Wv, const float* __restrict__ Wr,
    unsigned short* __restrict__ Wpk)
{
    int b = blockIdx.x;               // l*224 + kb*56 + jb
    int l = b / 224, rem = b % 224;
    int kb = rem / 56, jb = rem % 56;
    int lane = threadIdx.x;
    int j = jb * 16 + (lane & 15);
    int kbase = kb * 32 + ((lane >> 4) << 3);
    unsigned short* dst = Wpk + ((size_t)b * 64 + lane) * 8;
#pragma unroll
    for (int t = 0; t < 8; ++t) {
        int k = kbase + t;
        float v;
        if (j < 256)       v = Wq[((size_t)l * HD + k) * CDIM + j];
        else if (j < 512)  v = Wk[((size_t)l * HD + k) * CDIM + (j - 256)];
        else if (j < 768)  v = Wv[((size_t)l * HD + k) * CDIM + (j - 512)];
        else               v = Wr[((size_t)l * HD + k) * HD + (j - 768)];
        dst[t] = f2bf(v);
    }
}

// ---------------- CSR build ----------------
__global__ void k_hist_dst(const int* __restrict__ ei, int* __restrict__ cnt)
{
    int e = blockIdx.x * blockDim.x + threadIdx.x;
    if (e < NE) atomicAdd(&cnt[ei[NE + e]], 1);
}

__global__ __launch_bounds__(1024) void k_exscan(
    const int* __restrict__ in, int* __restrict__ out, int* __restrict__ out2, int n)
{
    __shared__ int sm[1024];
    int tid = threadIdx.x;
    int ch = (n + 1023) >> 10;
    int beg = tid * ch, end = min(beg + ch, n);
    int s = 0;
    for (int i = beg; i < end; ++i) s += in[i];
    sm[tid] = s;
    __syncthreads();
    for (int off = 1; off < 1024; off <<= 1) {
        int t = (tid >= off) ? sm[tid - off] : 0;
        __syncthreads();
        sm[tid] += t;
        __syncthreads();
    }
    int run = sm[tid] - s;
    for (int i = beg; i < end; ++i) { out[i] = run; if (out2) out2[i] = run; run += in[i]; }
    if (tid == 1023) { out[n] = sm[1023]; if (out2) out2[n] = sm[1023]; }
}

__global__ void k_scatter(const int* __restrict__ ei, const int* __restrict__ ea,
                          int* __restrict__ wof, int* __restrict__ csrc, int* __restrict__ cea)
{
    int e = blockIdx.x * blockDim.x + threadIdx.x;
    if (e < NE) {
        int d = ei[NE + e];
        int pos = atomicAdd(&wof[d], 1);
        csrc[pos] = ei[e];
        cea[pos]  = ea[e];
    }
}

__global__ void k_gptr(const int* __restrict__ batch, int* __restrict__ gptr)
{
    int g = blockIdx.x * blockDim.x + threadIdx.x;
    if (g > NGR) return;
    if (g == NGR) { gptr[g] = NN; return; }
    int lo = 0, hi = NN;
    while (lo < hi) { int mid = (lo + hi) >> 1; if (batch[mid] < g) lo = mid + 1; else hi = mid; }
    gptr[g] = lo;
}

// ---------------- x0[n] = x0table[x[n]] (fp32 + bf16) ----------------
__global__ void k_x0(const int* __restrict__ x, const float* __restrict__ tab,
                     float* __restrict__ x0, unsigned short* __restrict__ x0b)
{
    int idx = blockIdx.x * blockDim.x + threadIdx.x;  // NN*32 float4 slots
    if (idx >= NN * 32) return;
    int n = idx >> 5, c = idx & 31;
    float4 v = *(const float4*)&tab[x[n] * HD + c * 4];
    *(float4*)&x0[(size_t)n * HD + c * 4] = v;
    ushort4 u; u.x = f2bf(v.x); u.y = f2bf(v.y); u.z = f2bf(v.z); u.w = f2bf(v.w);
    *(ushort4*)&x0b[(size_t)n * HD + c * 4] = u;
}

// ---------------- bf16 MFMA GEMM: A[NN,128]bf16 x Wpk -> QKVR[NN,896]bf16 ----------------
__global__ __launch_bounds__(256) void k_gemm(
    const unsigned short* __restrict__ Ab, const unsigned short* __restrict__ Wpk,
    unsigned short* __restrict__ C)
{
    int lane = threadIdx.x & 63, wid = threadIdx.x >> 6;
    int row0 = blockIdx.x * 64 + wid * 16;
    int ar = row0 + (lane & 15);
    size_t arow = (size_t)((ar < NN) ? ar : (NN - 1));
    int ko = (lane >> 4) << 3;                    // k offset within 32-block
    const unsigned short* ap = Ab + arow * HD + ko;
    bf16x8 a0 = *(const bf16x8*)(ap);
    bf16x8 a1 = *(const bf16x8*)(ap + 32);
    bf16x8 a2 = *(const bf16x8*)(ap + 64);
    bf16x8 a3 = *(const bf16x8*)(ap + 96);

    const unsigned short* wp = Wpk + (size_t)lane * 8;
    int rb = row0 + ((lane >> 4) << 2);           // D rows rb..rb+3, col jb*16+(lane&15)
#pragma unroll 2
    for (int jb = 0; jb < 56; ++jb) {
        const unsigned short* bp = wp + (size_t)jb * 512;
        bf16x8 b0 = *(const bf16x8*)(bp);
        bf16x8 b1 = *(const bf16x8*)(bp + 28672);   // kb stride = 56*512
        bf16x8 b2 = *(const bf16x8*)(bp + 57344);
        bf16x8 b3 = *(const bf16x8*)(bp + 86016);
        f32x4 acc = {0.f, 0.f, 0.f, 0.f};
        acc = __builtin_amdgcn_mfma_f32_16x16x32_bf16(a0, b0, acc, 0, 0, 0);
        acc = __builtin_amdgcn_mfma_f32_16x16x32_bf16(a1, b1, acc, 0, 0, 0);
        acc = __builtin_amdgcn_mfma_f32_16x16x32_bf16(a2, b2, acc, 0, 0, 0);
        acc = __builtin_amdgcn_mfma_f32_16x16x32_bf16(a3, b3, acc, 0, 0, 0);
        int col = jb * 16 + (lane & 15);
        unsigned short* cp = C + (size_t)rb * NCAT + col;
        if (rb + 0 < NN) cp[0]        = f2bf(acc[0]);
        if (rb + 1 < NN) cp[NCAT]     = f2bf(acc[1]);
        if (rb + 2 < NN) cp[2 * NCAT] = f2bf(acc[2]);
        if (rb + 3 < NN) cp[3 * NCAT] = f2bf(acc[3]);
    }
}

// ---------------- per-node attention: wave per dst node, online softmax ----------------
__global__ __launch_bounds__(256) void k_edge(
    const unsigned short* __restrict__ QKVR,  // [NN][896] bf16
    const unsigned short* __restrict__ etab,  // [NVOC][256] bf16
    const float* __restrict__ attL, const float* __restrict__ biasL,
    const float* __restrict__ x0,
    const int* __restrict__ rowptr, const int* __restrict__ csrc, const int* __restrict__ cea,
    unsigned short* __restrict__ hb)          // [NN][128] bf16
{
    int wave = (blockIdx.x * blockDim.x + threadIdx.x) >> 6;
    if (wave >= NN) return;
    int n = wave;
    int lane = threadIdx.x & 63;
    int head = lane >> 5, sub = lane & 31;
    int col = head * HD + sub * 4;

    ushort4 qu = *(const ushort4*)&QKVR[(size_t)n * NCAT + col];
    float qx = bf2f(qu.x), qy = bf2f(qu.y), qz = bf2f(qu.z), qw = bf2f(qu.w);
    float4 a4 = *(const float4*)&attL[col];

    float m = -INFINITY, l = 0.f;
    float4 acc = {0.f, 0.f, 0.f, 0.f};

    int beg = rowptr[n], end = rowptr[n + 1];
    for (int idx = beg; idx < end; ++idx) {
        int s = csrc[idx], a = cea[idx];
        const unsigned short* sp = QKVR + (size_t)s * NCAT;
        ushort4 ku = *(const ushort4*)&sp[256 + col];
        ushort4 eu = *(const ushort4*)&etab[a * CDIM + col];
        ushort4 vu = *(const ushort4*)&sp[512 + col];
        float ex = bf2f(eu.x), ey = bf2f(eu.y), ez = bf2f(eu.z), ew = bf2f(eu.w);
        float zx = qx + bf2f(ku.x) + ex; zx = (zx > 0.f) ? zx : 0.2f * zx;
        float zy = qy + bf2f(ku.y) + ey; zy = (zy > 0.f) ? zy : 0.2f * zy;
        float zz = qz + bf2f(ku.z) + ez; zz = (zz > 0.f) ? zz : 0.2f * zz;
        float zw = qw + bf2f(ku.w) + ew; zw = (zw > 0.f) ? zw : 0.2f * zw;
        float p = zx * a4.x + zy * a4.y + zz * a4.z + zw * a4.w;
        p += __shfl_xor(p, 16); p += __shfl_xor(p, 8);
        p += __shfl_xor(p, 4);  p += __shfl_xor(p, 2); p += __shfl_xor(p, 1);
        float wx = bf2f(vu.x) + ex, wy = bf2f(vu.y) + ey;
        float wz = bf2f(vu.z) + ez, ww = bf2f(vu.w) + ew;
        float mn = fmaxf(m, p);
        float sc = __expf(m - mn);
        float pe = __expf(p - mn);
        acc.x = acc.x * sc + pe * wx;
        acc.y = acc.y * sc + pe * wy;
        acc.z = acc.z * sc + pe * wz;
        acc.w = acc.w * sc + pe * ww;
        l = l * sc + pe;
        m = mn;
    }
    float invl = (l > 0.f) ? 1.0f / l : 0.f;
    float ax = acc.x * invl, ay = acc.y * invl, az = acc.z * invl, aw = acc.w * invl;
    ax = 0.5f * (ax + __shfl_xor(ax, 32));
    ay = 0.5f * (ay + __shfl_xor(ay, 32));
    az = 0.5f * (az + __shfl_xor(az, 32));
    aw = 0.5f * (aw + __shfl_xor(aw, 32));
    if (head == 0) {
        ushort4 ru = *(const ushort4*)&QKVR[(size_t)n * NCAT + 768 + sub * 4];
        float4 b4 = *(const float4*)&biasL[sub * 4];
        float4 x4 = *(const float4*)&x0[(size_t)n * HD + sub * 4];
        float ox = 0.9f * fmaxf(ax + bf2f(ru.x) + b4.x, 0.f) + 0.1f * x4.x;
        float oy = 0.9f * fmaxf(ay + bf2f(ru.y) + b4.y, 0.f) + 0.1f * x4.y;
        float oz = 0.9f * fmaxf(az + bf2f(ru.z) + b4.z, 0.f) + 0.1f * x4.z;
        float ow = 0.9f * fmaxf(aw + bf2f(ru.w) + b4.w, 0.f) + 0.1f * x4.w;
        ushort4 o; o.x = f2bf(ox); o.y = f2bf(oy); o.z = f2bf(oz); o.w = f2bf(ow);
        *(ushort4*)&hb[(size_t)n * HD + sub * 4] = o;
    }
}

// ---------------- pooling: block per graph, sum one 128-slice (bf16 src) ----------------
__global__ __launch_bounds__(128) void k_pool(
    const unsigned short* __restrict__ src, const int* __restrict__ gptr,
    float* __restrict__ gsum, int slice)
{
    int g = blockIdx.x, d = threadIdx.x;
    int beg = gptr[g], end = gptr[g + 1];
    float s = 0.f;
    for (int n = beg; n < end; ++n) s += bf2f(src[(size_t)n * HD + d]);
    gsum[(size_t)g * 640 + slice * HD + d] = s;
}

// ---------------- final MLP: g[640] -> 128 -> 1 ----------------
__global__ __launch_bounds__(128) void k_out(
    const float* __restrict__ gsum, const int* __restrict__ gptr,
    const float* __restrict__ w1, const float* __restrict__ b1,
    const float* __restrict__ g1, const float* __restrict__ bt1,
    const float* __restrict__ w2, const float* __restrict__ b2,
    float* __restrict__ out)
{
    int g = blockIdx.x, d = threadIdx.x;
    __shared__ float row[640];
    __shared__ float red[2];
    int c = gptr[g + 1] - gptr[g];
    float invc = 1.0f / (float)max(c, 1);
    for (int j = d; j < 640; j += 128) row[j] = gsum[(size_t)g * 640 + j] * invc;
    __syncthreads();
    float acc = b1[d];
    for (int j = 0; j < 640; ++j) acc += row[j] * w1[j * HD + d];
    float val = fmaxf(acc * BN_INV * g1[d] + bt1[d], 0.f);
    float part = val * w2[d];
    part += __shfl_xor(part, 32); part += __shfl_xor(part, 16);
    part += __shfl_xor(part, 8);  part += __shfl_xor(part, 4);
    part += __shfl_xor(part, 2);  part += __shfl_xor(part, 1);
    if ((threadIdx.x & 63) == 0) red[threadIdx.x >> 6] = part;
    __syncthreads();
    if (threadIdx.x == 0) out[g] = red[0] + red[1] + b2[0];
}

// ---------------- launch ----------------
extern "C" void kernel_launch(void* const* d_in, const int* in_sizes, int n_in,
                              void* d_out, int out_size, void* d_ws, size_t ws_size,
                              hipStream_t stream)
{
    const int*   x        = (const int*)d_in[0];
    const int*   ei       = (const int*)d_in[1];
    const int*   ea       = (const int*)d_in[2];
    const int*   batch    = (const int*)d_in[3];
    const float* node_emb = (const float*)d_in[4];
    const float* emb_w1   = (const float*)d_in[5];
    const float* emb_b1   = (const float*)d_in[6];
    const float* emb_g1   = (const float*)d_in[7];
    const float* emb_bt1  = (const float*)d_in[8];
    const float* emb_w2   = (const float*)d_in[9];
    const float* emb_b2   = (const float*)d_in[10];
    const float* bn0_g    = (const float*)d_in[11];
    const float* bn0_b    = (const float*)d_in[12];
    const float* Wq       = (const float*)d_in[13];
    const float* Wk       = (const float*)d_in[14];
    const float* Wv       = (const float*)d_in[15];
    const float* We       = (const float*)d_in[16];
    const float* att      = (const float*)d_in[17];
    const float* Wroot    = (const float*)d_in[18];
    const float* bias     = (const float*)d_in[19];
    const float* out_w1   = (const float*)d_in[20];
    const float* out_b1   = (const float*)d_in[21];
    const float* out_g1   = (const float*)d_in[22];
    const float* out_bt1  = (const float*)d_in[23];
    const float* out_w2   = (const float*)d_in[24];
    const float* out_b2   = (const float*)d_in[25];

    char* wp = (char*)d_ws;
    auto alloc = [&](size_t bytes) -> void* {
        void* p = (void*)wp;
        wp += (bytes + 255) & ~(size_t)255;
        return p;
    };
    float*          x0    = (float*)alloc((size_t)NN * HD * 4);
    unsigned short* x0b   = (unsigned short*)alloc((size_t)NN * HD * 2);
    unsigned short* hbA   = (unsigned short*)alloc((size_t)NN * HD * 2);
    unsigned short* hbB   = (unsigned short*)alloc((size_t)NN * HD * 2);
    unsigned short* QKVR  = (unsigned short*)alloc((size_t)NN * NCAT * 2);
    float*          x0tab = (float*)alloc((size_t)NVOC * HD * 4);
    unsigned short* etab  = (unsigned short*)alloc((size_t)NLAY * NVOC * CDIM * 2);
    unsigned short* Wpk   = (unsigned short*)alloc((size_t)NLAY * 224 * 64 * 8 * 2);
    int*   cnt   = (int*)alloc((size_t)NN * 4);
    int*   rowp  = (int*)alloc((size_t)(NN + 1) * 4);
    int*   wof   = (int*)alloc((size_t)(NN + 1) * 4);
    int*   csrc  = (int*)alloc((size_t)NE * 4);
    int*   ceaB  = (int*)alloc((size_t)NE * 4);
    int*   gptr  = (int*)alloc((size_t)(NGR + 1) * 4);
    float* gsum  = (float*)alloc((size_t)NGR * 640 * 4);

    hipMemsetAsync(cnt, 0, (size_t)NN * 4, stream);

    k_tables_node<<<NVOC, 128, 0, stream>>>(node_emb, emb_w1, emb_b1, emb_g1, emb_bt1,
                                            emb_w2, emb_b2, bn0_g, bn0_b, x0tab);
    k_tables_edge<<<NLAY * NVOC, 256, 0, stream>>>(node_emb, We, etab);
    k_packw<<<NLAY * 224, 64, 0, stream>>>(Wq, Wk, Wv, Wroot, Wpk);
    k_hist_dst<<<(NE + 255) / 256, 256, 0, stream>>>(ei, cnt);
    k_exscan<<<1, 1024, 0, stream>>>(cnt, rowp, wof, NN);
    k_scatter<<<(NE + 255) / 256, 256, 0, stream>>>(ei, ea, wof, csrc, ceaB);
    k_gptr<<<(NGR + 1 + 255) / 256, 256, 0, stream>>>(batch, gptr);
    k_x0<<<(NN * 32 + 255) / 256, 256, 0, stream>>>(x, x0tab, x0, x0b);
    k_pool<<<NGR, 128, 0, stream>>>(x0b, gptr, gsum, 0);

    const unsigned short* hin = x0b;
    unsigned short* houts[NLAY] = {hbA, hbB, hbA, hbB};
    for (int l = 0; l < NLAY; ++l) {
        k_gemm<<<(NN + 63) / 64, 256, 0, stream>>>(hin, Wpk + (size_t)l * 224 * 512, QKVR);
        k_edge<<<(NN * 64 + 255) / 256, 256, 0, stream>>>(
            QKVR, etab + (size_t)l * NVOC * CDIM, att + (size_t)l * CDIM, bias + (size_t)l * HD,
            x0, rowp, csrc, ceaB, houts[l]);
        k_pool<<<NGR, 128, 0, stream>>>(houts[l], gptr, gsum, l + 1);
        hin = houts[l];
    }
    k_out<<<NGR, 128, 0, stream>>>(gsum, gptr, out_w1, out_b1, out_g1, out_bt1,
                                   out_w2, out_b2, (float*)d_out);
}

// Round 3
// 657.591 us; speedup vs baseline: 2.1146x; 1.1516x over previous
//
#include <hip/hip_runtime.h>
#include <hip/hip_bf16.h>

#define NN 50000      // nodes
#define NE 200000     // edges
#define NGR 500       // graphs
#define HD 128        // hidden
#define CDIM 256      // H*DH
#define NLAY 4
#define NVOC 30
#define NCAT 896      // 256*3 + 128 : Q|K|V|R concatenated
#define SCH 256                       // scan chunk
#define SNB ((NN + SCH - 1) / SCH)    // 196 scan blocks

static constexpr float BN_INV = 0.9999950000374997f;  // 1/sqrt(1+1e-5)

typedef __attribute__((ext_vector_type(8))) short bf16x8;
typedef __attribute__((ext_vector_type(4))) float f32x4;

__device__ __forceinline__ float bf2f(unsigned short u) {
    return __uint_as_float(((unsigned)u) << 16);
}
__device__ __forceinline__ unsigned short f2bf(float f) {
    union { __hip_bfloat16 h; unsigned short u; } cv;
    cv.h = __float2bfloat16(f);
    return cv.u;
}

// ---------------- tables: x0table[30][128] = emb MLP (fp32) ----------------
__global__ __launch_bounds__(128) void k_tables_node(
    const float* __restrict__ ne, const float* __restrict__ w1, const float* __restrict__ b1,
    const float* __restrict__ g1, const float* __restrict__ bt1,
    const float* __restrict__ w2, const float* __restrict__ b2,
    const float* __restrict__ g0, const float* __restrict__ bt0,
    float* __restrict__ x0tab)
{
    int r = blockIdx.x, d = threadIdx.x;
    __shared__ float emb[HD], t1[HD];
    emb[d] = ne[r * HD + d];
    __syncthreads();
    float acc = b1[d];
    for (int k = 0; k < HD; ++k) acc += emb[k] * w1[k * HD + d];
    float t = fmaxf(acc * BN_INV * g1[d] + bt1[d], 0.f);
    t1[d] = t;
    __syncthreads();
    float acc2 = b2[d];
    for (int k = 0; k < HD; ++k) acc2 += t1[k] * w2[k * HD + d];
    x0tab[r * HD + d] = fmaxf(acc2 * BN_INV * g0[d] + bt0[d], 0.f);
}

// ---------------- tables: etab[l][30][256] bf16 = node_emb @ We[l] ----------------
__global__ __launch_bounds__(256) void k_tables_edge(
    const float* __restrict__ ne, const float* __restrict__ We, unsigned short* __restrict__ etab)
{
    int la = blockIdx.x;              // l*NVOC + a
    int l = la / NVOC, a = la % NVOC;
    int c = threadIdx.x;              // 0..255
    __shared__ float emb[HD];
    if (c < HD) emb[c] = ne[a * HD + c];
    __syncthreads();
    const float* W = We + (size_t)l * HD * CDIM;
    float acc = 0.f;
    for (int k = 0; k < HD; ++k) acc += emb[k] * W[k * CDIM + c];
    etab[(size_t)la * CDIM + c] = f2bf(acc);
}

// ---------------- pack weights: Wpk[l][kb][jb][lane][8] bf16 ----------------
__global__ __launch_bounds__(64) void k_packw(
    const float* __restrict__ Wq, const float* __restrict__ Wk,
    const float* __restrict__ Wv, const float* __restrict__ Wr,
    unsigned short* __restrict__ Wpk)
{
    int b = blockIdx.x;               // l*224 + kb*56 + jb
    int l = b / 224, rem = b % 224;
    int kb = rem / 56, jb = rem % 56;
    int lane = threadIdx.x;
    int j = jb * 16 + (lane & 15);
    int kbase = kb * 32 + ((lane >> 4) << 3);
    unsigned short* dst = Wpk + ((size_t)b * 64 + lane) * 8;
#pragma unroll
    for (int t = 0; t < 8; ++t) {
        int k = kbase + t;
        float v;
        if (j < 256)       v = Wq[((size_t)l * HD + k) * CDIM + j];
        else if (j < 512)  v = Wk[((size_t)l * HD + k) * CDIM + (j - 256)];
        else if (j < 768)  v = Wv[((size_t)l * HD + k) * CDIM + (j - 512)];
        else               v = Wr[((size_t)l * HD + k) * HD + (j - 768)];
        dst[t] = f2bf(v);
    }
}

// ---------------- CSR build ----------------
__global__ void k_hist_dst(const int* __restrict__ ei, int* __restrict__ cnt)
{
    int e = blockIdx.x * blockDim.x + threadIdx.x;
    if (e < NE) atomicAdd(&cnt[ei[NE + e]], 1);
}

// stage 1: per-block sums of 256-element chunks
__global__ __launch_bounds__(256) void k_blocksum(const int* __restrict__ cnt, int* __restrict__ part)
{
    int t = threadIdx.x;
    int i = blockIdx.x * SCH + t;
    int v = (i < NN) ? cnt[i] : 0;
    __shared__ int sm[256];
    sm[t] = v;
    __syncthreads();
    for (int off = 128; off; off >>= 1) {
        if (t < off) sm[t] += sm[t + off];
        __syncthreads();
    }
    if (t == 0) part[blockIdx.x] = sm[0];
}

// stage 2: exclusive scan of the SNB partials (single small block)
__global__ __launch_bounds__(256) void k_scanpart(int* __restrict__ part)
{
    int t = threadIdx.x;
    int v = (t < SNB) ? part[t] : 0;
    __shared__ int sm[256];
    sm[t] = v;
    __syncthreads();
    for (int off = 1; off < 256; off <<= 1) {
        int u = (t >= off) ? sm[t - off] : 0;
        __syncthreads();
        sm[t] += u;
        __syncthreads();
    }
    if (t < SNB) part[t] = sm[t] - v;   // exclusive
}

// stage 3: in-block scan + base, write rowp & wof
__global__ __launch_bounds__(256) void k_csrwrite(
    const int* __restrict__ cnt, const int* __restrict__ part,
    int* __restrict__ rowp, int* __restrict__ wof)
{
    int t = threadIdx.x;
    int i = blockIdx.x * SCH + t;
    int v = (i < NN) ? cnt[i] : 0;
    __shared__ int sm[256];
    sm[t] = v;
    __syncthreads();
    for (int off = 1; off < 256; off <<= 1) {
        int u = (t >= off) ? sm[t - off] : 0;
        __syncthreads();
        sm[t] += u;
        __syncthreads();
    }
    int excl = sm[t] - v + part[blockIdx.x];
    if (i < NN) { rowp[i] = excl; wof[i] = excl; }
    if (i == NN - 1) rowp[NN] = excl + v;   // = NE
}

__global__ void k_scatter(const int* __restrict__ ei, const int* __restrict__ ea,
                          int* __restrict__ wof, int* __restrict__ csrc, int* __restrict__ cea)
{
    int e = blockIdx.x * blockDim.x + threadIdx.x;
    if (e < NE) {
        int d = ei[NE + e];
        int pos = atomicAdd(&wof[d], 1);
        csrc[pos] = ei[e];
        cea[pos]  = ea[e];
    }
}

__global__ void k_gptr(const int* __restrict__ batch, int* __restrict__ gptr)
{
    int g = blockIdx.x * blockDim.x + threadIdx.x;
    if (g > NGR) return;
    if (g == NGR) { gptr[g] = NN; return; }
    int lo = 0, hi = NN;
    while (lo < hi) { int mid = (lo + hi) >> 1; if (batch[mid] < g) lo = mid + 1; else hi = mid; }
    gptr[g] = lo;
}

// ---------------- x0[n] = x0table[x[n]] (fp32 + bf16) ----------------
__global__ void k_x0(const int* __restrict__ x, const float* __restrict__ tab,
                     float* __restrict__ x0, unsigned short* __restrict__ x0b)
{
    int idx = blockIdx.x * blockDim.x + threadIdx.x;  // NN*32 float4 slots
    if (idx >= NN * 32) return;
    int n = idx >> 5, c = idx & 31;
    float4 v = *(const float4*)&tab[x[n] * HD + c * 4];
    *(float4*)&x0[(size_t)n * HD + c * 4] = v;
    ushort4 u; u.x = f2bf(v.x); u.y = f2bf(v.y); u.z = f2bf(v.z); u.w = f2bf(v.w);
    *(ushort4*)&x0b[(size_t)n * HD + c * 4] = u;
}

// ---------------- bf16 MFMA GEMM: A[NN,128]bf16 x Wpk -> QKVR[NN,896]bf16 ----------------
__global__ __launch_bounds__(256) void k_gemm(
    const unsigned short* __restrict__ Ab, const unsigned short* __restrict__ Wpk,
    unsigned short* __restrict__ C)
{
    int lane = threadIdx.x & 63, wid = threadIdx.x >> 6;
    int row0 = blockIdx.x * 64 + wid * 16;
    int ar = row0 + (lane & 15);
    size_t arow = (size_t)((ar < NN) ? ar : (NN - 1));
    int ko = (lane >> 4) << 3;
    const unsigned short* ap = Ab + arow * HD + ko;
    bf16x8 a0 = *(const bf16x8*)(ap);
    bf16x8 a1 = *(const bf16x8*)(ap + 32);
    bf16x8 a2 = *(const bf16x8*)(ap + 64);
    bf16x8 a3 = *(const bf16x8*)(ap + 96);

    const unsigned short* wp = Wpk + (size_t)lane * 8;
    int rb = row0 + ((lane >> 4) << 2);
#pragma unroll 2
    for (int jb = 0; jb < 56; ++jb) {
        const unsigned short* bp = wp + (size_t)jb * 512;
        bf16x8 b0 = *(const bf16x8*)(bp);
        bf16x8 b1 = *(const bf16x8*)(bp + 28672);
        bf16x8 b2 = *(const bf16x8*)(bp + 57344);
        bf16x8 b3 = *(const bf16x8*)(bp + 86016);
        f32x4 acc = {0.f, 0.f, 0.f, 0.f};
        acc = __builtin_amdgcn_mfma_f32_16x16x32_bf16(a0, b0, acc, 0, 0, 0);
        acc = __builtin_amdgcn_mfma_f32_16x16x32_bf16(a1, b1, acc, 0, 0, 0);
        acc = __builtin_amdgcn_mfma_f32_16x16x32_bf16(a2, b2, acc, 0, 0, 0);
        acc = __builtin_amdgcn_mfma_f32_16x16x32_bf16(a3, b3, acc, 0, 0, 0);
        int col = jb * 16 + (lane & 15);
        unsigned short* cp = C + (size_t)rb * NCAT + col;
        if (rb + 0 < NN) cp[0]        = f2bf(acc[0]);
        if (rb + 1 < NN) cp[NCAT]     = f2bf(acc[1]);
        if (rb + 2 < NN) cp[2 * NCAT] = f2bf(acc[2]);
        if (rb + 3 < NN) cp[3 * NCAT] = f2bf(acc[3]);
    }
}

// ---------------- per-node attention: wave per dst node, online softmax ----------------
__global__ __launch_bounds__(256) void k_edge(
    const unsigned short* __restrict__ QKVR,  // [NN][896] bf16
    const unsigned short* __restrict__ etab,  // [NVOC][256] bf16
    const float* __restrict__ attL, const float* __restrict__ biasL,
    const float* __restrict__ x0,
    const int* __restrict__ rowptr, const int* __restrict__ csrc, const int* __restrict__ cea,
    unsigned short* __restrict__ hb)          // [NN][128] bf16
{
    int wave = (blockIdx.x * blockDim.x + threadIdx.x) >> 6;
    if (wave >= NN) return;
    int n = wave;
    int lane = threadIdx.x & 63;
    int head = lane >> 5, sub = lane & 31;
    int col = head * HD + sub * 4;

    ushort4 qu = *(const ushort4*)&QKVR[(size_t)n * NCAT + col];
    float qx = bf2f(qu.x), qy = bf2f(qu.y), qz = bf2f(qu.z), qw = bf2f(qu.w);
    float4 a4 = *(const float4*)&attL[col];

    float m = -INFINITY, l = 0.f;
    float4 acc = {0.f, 0.f, 0.f, 0.f};

    int beg = rowptr[n], end = rowptr[n + 1];
    for (int idx = beg; idx < end; ++idx) {
        int s = csrc[idx], a = cea[idx];
        const unsigned short* sp = QKVR + (size_t)s * NCAT;
        ushort4 ku = *(const ushort4*)&sp[256 + col];
        ushort4 eu = *(const ushort4*)&etab[a * CDIM + col];
        ushort4 vu = *(const ushort4*)&sp[512 + col];
        float ex = bf2f(eu.x), ey = bf2f(eu.y), ez = bf2f(eu.z), ew = bf2f(eu.w);
        float zx = qx + bf2f(ku.x) + ex; zx = (zx > 0.f) ? zx : 0.2f * zx;
        float zy = qy + bf2f(ku.y) + ey; zy = (zy > 0.f) ? zy : 0.2f * zy;
        float zz = qz + bf2f(ku.z) + ez; zz = (zz > 0.f) ? zz : 0.2f * zz;
        float zw = qw + bf2f(ku.w) + ew; zw = (zw > 0.f) ? zw : 0.2f * zw;
        float p = zx * a4.x + zy * a4.y + zz * a4.z + zw * a4.w;
        p += __shfl_xor(p, 16); p += __shfl_xor(p, 8);
        p += __shfl_xor(p, 4);  p += __shfl_xor(p, 2); p += __shfl_xor(p, 1);
        float wx = bf2f(vu.x) + ex, wy = bf2f(vu.y) + ey;
        float wz = bf2f(vu.z) + ez, ww = bf2f(vu.w) + ew;
        float mn = fmaxf(m, p);
        float sc = __expf(m - mn);
        float pe = __expf(p - mn);
        acc.x = acc.x * sc + pe * wx;
        acc.y = acc.y * sc + pe * wy;
        acc.z = acc.z * sc + pe * wz;
        acc.w = acc.w * sc + pe * ww;
        l = l * sc + pe;
        m = mn;
    }
    float invl = (l > 0.f) ? 1.0f / l : 0.f;
    float ax = acc.x * invl, ay = acc.y * invl, az = acc.z * invl, aw = acc.w * invl;
    ax = 0.5f * (ax + __shfl_xor(ax, 32));
    ay = 0.5f * (ay + __shfl_xor(ay, 32));
    az = 0.5f * (az + __shfl_xor(az, 32));
    aw = 0.5f * (aw + __shfl_xor(aw, 32));
    if (head == 0) {
        ushort4 ru = *(const ushort4*)&QKVR[(size_t)n * NCAT + 768 + sub * 4];
        float4 b4 = *(const float4*)&biasL[sub * 4];
        float4 x4 = *(const float4*)&x0[(size_t)n * HD + sub * 4];
        float ox = 0.9f * fmaxf(ax + bf2f(ru.x) + b4.x, 0.f) + 0.1f * x4.x;
        float oy = 0.9f * fmaxf(ay + bf2f(ru.y) + b4.y, 0.f) + 0.1f * x4.y;
        float oz = 0.9f * fmaxf(az + bf2f(ru.z) + b4.z, 0.f) + 0.1f * x4.z;
        float ow = 0.9f * fmaxf(aw + bf2f(ru.w) + b4.w, 0.f) + 0.1f * x4.w;
        ushort4 o; o.x = f2bf(ox); o.y = f2bf(oy); o.z = f2bf(oz); o.w = f2bf(ow);
        *(ushort4*)&hb[(size_t)n * HD + sub * 4] = o;
    }
}

// ---------------- pooling: block per graph, sum one 128-slice (bf16 src) ----------------
__global__ __launch_bounds__(128) void k_pool(
    const unsigned short* __restrict__ src, const int* __restrict__ gptr,
    float* __restrict__ gsum, int slice)
{
    int g = blockIdx.x, d = threadIdx.x;
    int beg = gptr[g], end = gptr[g + 1];
    float s = 0.f;
    for (int n = beg; n < end; ++n) s += bf2f(src[(size_t)n * HD + d]);
    gsum[(size_t)g * 640 + slice * HD + d] = s;
}

// ---------------- final MLP: g[640] -> 128 -> 1 ----------------
__global__ __launch_bounds__(128) void k_out(
    const float* __restrict__ gsum, const int* __restrict__ gptr,
    const float* __restrict__ w1, const float* __restrict__ b1,
    const float* __restrict__ g1, const float* __restrict__ bt1,
    const float* __restrict__ w2, const float* __restrict__ b2,
    float* __restrict__ out)
{
    int g = blockIdx.x, d = threadIdx.x;
    __shared__ float row[640];
    __shared__ float red[2];
    int c = gptr[g + 1] - gptr[g];
    float invc = 1.0f / (float)max(c, 1);
    for (int j = d; j < 640; j += 128) row[j] = gsum[(size_t)g * 640 + j] * invc;
    __syncthreads();
    float acc = b1[d];
    for (int j = 0; j < 640; ++j) acc += row[j] * w1[j * HD + d];
    float val = fmaxf(acc * BN_INV * g1[d] + bt1[d], 0.f);
    float part = val * w2[d];
    part += __shfl_xor(part, 32); part += __shfl_xor(part, 16);
    part += __shfl_xor(part, 8);  part += __shfl_xor(part, 4);
    part += __shfl_xor(part, 2);  part += __shfl_xor(part, 1);
    if ((threadIdx.x & 63) == 0) red[threadIdx.x >> 6] = part;
    __syncthreads();
    if (threadIdx.x == 0) out[g] = red[0] + red[1] + b2[0];
}

// ---------------- launch ----------------
extern "C" void kernel_launch(void* const* d_in, const int* in_sizes, int n_in,
                              void* d_out, int out_size, void* d_ws, size_t ws_size,
                              hipStream_t stream)
{
    const int*   x        = (const int*)d_in[0];
    const int*   ei       = (const int*)d_in[1];
    const int*   ea       = (const int*)d_in[2];
    const int*   batch    = (const int*)d_in[3];
    const float* node_emb = (const float*)d_in[4];
    const float* emb_w1   = (const float*)d_in[5];
    const float* emb_b1   = (const float*)d_in[6];
    const float* emb_g1   = (const float*)d_in[7];
    const float* emb_bt1  = (const float*)d_in[8];
    const float* emb_w2   = (const float*)d_in[9];
    const float* emb_b2   = (const float*)d_in[10];
    const float* bn0_g    = (const float*)d_in[11];
    const float* bn0_b    = (const float*)d_in[12];
    const float* Wq       = (const float*)d_in[13];
    const float* Wk       = (const float*)d_in[14];
    const float* Wv       = (const float*)d_in[15];
    const float* We       = (const float*)d_in[16];
    const float* att      = (const float*)d_in[17];
    const float* Wroot    = (const float*)d_in[18];
    const float* bias     = (const float*)d_in[19];
    const float* out_w1   = (const float*)d_in[20];
    const float* out_b1   = (const float*)d_in[21];
    const float* out_g1   = (const float*)d_in[22];
    const float* out_bt1  = (const float*)d_in[23];
    const float* out_w2   = (const float*)d_in[24];
    const float* out_b2   = (const float*)d_in[25];

    char* wp = (char*)d_ws;
    auto alloc = [&](size_t bytes) -> void* {
        void* p = (void*)wp;
        wp += (bytes + 255) & ~(size_t)255;
        return p;
    };
    float*          x0    = (float*)alloc((size_t)NN * HD * 4);
    unsigned short* x0b   = (unsigned short*)alloc((size_t)NN * HD * 2);
    unsigned short* hbA   = (unsigned short*)alloc((size_t)NN * HD * 2);
    unsigned short* hbB   = (unsigned short*)alloc((size_t)NN * HD * 2);
    unsigned short* QKVR  = (unsigned short*)alloc((size_t)NN * NCAT * 2);
    float*          x0tab = (float*)alloc((size_t)NVOC * HD * 4);
    unsigned short* etab  = (unsigned short*)alloc((size_t)NLAY * NVOC * CDIM * 2);
    unsigned short* Wpk   = (unsigned short*)alloc((size_t)NLAY * 224 * 64 * 8 * 2);
    int*   cnt   = (int*)alloc((size_t)NN * 4);
    int*   rowp  = (int*)alloc((size_t)(NN + 1) * 4);
    int*   wof   = (int*)alloc((size_t)(NN + 1) * 4);
    int*   part  = (int*)alloc((size_t)SNB * 4);
    int*   csrc  = (int*)alloc((size_t)NE * 4);
    int*   ceaB  = (int*)alloc((size_t)NE * 4);
    int*   gptr  = (int*)alloc((size_t)(NGR + 1) * 4);
    float* gsum  = (float*)alloc((size_t)NGR * 640 * 4);

    hipMemsetAsync(cnt, 0, (size_t)NN * 4, stream);

    k_tables_node<<<NVOC, 128, 0, stream>>>(node_emb, emb_w1, emb_b1, emb_g1, emb_bt1,
                                            emb_w2, emb_b2, bn0_g, bn0_b, x0tab);
    k_tables_edge<<<NLAY * NVOC, 256, 0, stream>>>(node_emb, We, etab);
    k_packw<<<NLAY * 224, 64, 0, stream>>>(Wq, Wk, Wv, Wroot, Wpk);
    k_hist_dst<<<(NE + 255) / 256, 256, 0, stream>>>(ei, cnt);
    k_blocksum<<<SNB, 256, 0, stream>>>(cnt, part);
    k_scanpart<<<1, 256, 0, stream>>>(part);
    k_csrwrite<<<SNB, 256, 0, stream>>>(cnt, part, rowp, wof);
    k_scatter<<<(NE + 255) / 256, 256, 0, stream>>>(ei, ea, wof, csrc, ceaB);
    k_gptr<<<(NGR + 1 + 255) / 256, 256, 0, stream>>>(batch, gptr);
    k_x0<<<(NN * 32 + 255) / 256, 256, 0, stream>>>(x, x0tab, x0, x0b);
    k_pool<<<NGR, 128, 0, stream>>>(x0b, gptr, gsum, 0);

    const unsigned short* hin = x0b;
    unsigned short* houts[NLAY] = {hbA, hbB, hbA, hbB};
    for (int l = 0; l < NLAY; ++l) {
        k_gemm<<<(NN + 63) / 64, 256, 0, stream>>>(hin, Wpk + (size_t)l * 224 * 512, QKVR);
        k_edge<<<(NN * 64 + 255) / 256, 256, 0, stream>>>(
            QKVR, etab + (size_t)l * NVOC * CDIM, att + (size_t)l * CDIM, bias + (size_t)l * HD,
            x0, rowp, csrc, ceaB, houts[l]);
        k_pool<<<NGR, 128, 0, stream>>>(houts[l], gptr, gsum, l + 1);
        hin = houts[l];
    }
    k_out<<<NGR, 128, 0, stream>>>(gsum, gptr, out_w1, out_b1, out_g1, out_bt1,
                                   out_w2, out_b2, (float*)d_out);
}